// Round 1
// baseline (613.642 us; speedup 1.0000x reference)
//
#include <hip/hip_runtime.h>
#include <hip/hip_bf16.h>

#define LEAK 0.2f

// ---------------- CSR build ----------------

__global__ __launch_bounds__(256) void k_hist(const int* __restrict__ edst,
                                              int* __restrict__ cnt, int E, int ETOT) {
    int e = blockIdx.x * 256 + threadIdx.x;
    if (e >= ETOT) return;
    int d = (e < E) ? edst[e] : (e - E);
    atomicAdd(&cnt[d], 1);
}

__global__ __launch_bounds__(1024) void k_scan1(const int* __restrict__ cnt,
                                                int* __restrict__ off,
                                                int* __restrict__ bsum, int N) {
    int i = blockIdx.x * 1024 + threadIdx.x;
    int v = (i < N) ? cnt[i] : 0;
    int lane = threadIdx.x & 63, wid = threadIdx.x >> 6;
    int x = v;
    #pragma unroll
    for (int o = 1; o < 64; o <<= 1) {
        int y = __shfl_up(x, o);
        if (lane >= o) x += y;
    }
    __shared__ int wsum[16];
    if (lane == 63) wsum[wid] = x;
    __syncthreads();
    if (wid == 0) {
        int s = (lane < 16) ? wsum[lane] : 0;
        #pragma unroll
        for (int o = 1; o < 16; o <<= 1) {
            int y = __shfl_up(s, o);
            if (lane >= o) s += y;
        }
        if (lane < 16) wsum[lane] = s;   // inclusive wave sums
    }
    __syncthreads();
    int waveoff = (wid > 0) ? wsum[wid - 1] : 0;
    int incl = x + waveoff;
    if (i < N) off[i] = incl - v;        // exclusive within block
    if (threadIdx.x == 1023) bsum[blockIdx.x] = incl;
}

__global__ void k_scan2(const int* __restrict__ bsum, int* __restrict__ boff,
                        int* __restrict__ off, int N, int nb) {
    int lane = threadIdx.x;   // 64 threads
    int v = (lane < nb) ? bsum[lane] : 0;
    int x = v;
    #pragma unroll
    for (int o = 1; o < 64; o <<= 1) {
        int y = __shfl_up(x, o);
        if (lane >= o) x += y;
    }
    if (lane < nb) boff[lane] = x - v;   // exclusive
    if (lane == 63) off[N] = x;          // grand total
}

__global__ __launch_bounds__(1024) void k_scan3(int* __restrict__ off,
                                                const int* __restrict__ boff,
                                                int* __restrict__ cur, int N) {
    int i = blockIdx.x * 1024 + threadIdx.x;
    if (i >= N) return;
    int o = off[i] + boff[blockIdx.x];
    off[i] = o;
    cur[i] = o;
}

__global__ __launch_bounds__(256) void k_scatter(const int* __restrict__ esrc,
                                                 const int* __restrict__ edst,
                                                 int* __restrict__ cur,
                                                 int* __restrict__ csr, int E, int ETOT) {
    int e = blockIdx.x * 256 + threadIdx.x;
    if (e >= ETOT) return;
    int s, d;
    if (e < E) { s = esrc[e]; d = edst[e]; } else { s = d = e - E; }
    int pos = atomicAdd(&cur[d], 1);
    csr[pos] = s;
}

// ---------------- GEMM: h = X @ W   (X:[N,128], W:[128,128]) ----------------

__global__ __launch_bounds__(256) void k_gemm(const float* __restrict__ X,
                                              const float* __restrict__ W,
                                              float* __restrict__ Hout, int N) {
    __shared__ float Xs[16][128];
    int block_row = blockIdx.x * 16;
    int t = threadIdx.x;
    for (int i = t; i < 16 * 128; i += 256) {
        int r = i >> 7, c = i & 127;
        int gr = block_row + r;
        Xs[r][c] = (gr < N) ? X[gr * 128 + c] : 0.f;
    }
    __syncthreads();
    int j = t & 127;     // output column
    int r0 = t >> 7;     // 0 or 1; thread covers rows r0, r0+2, ..., r0+14
    float acc[8];
    #pragma unroll
    for (int i = 0; i < 8; ++i) acc[i] = 0.f;
    for (int k4 = 0; k4 < 32; ++k4) {
        float w0 = W[(4 * k4 + 0) * 128 + j];
        float w1 = W[(4 * k4 + 1) * 128 + j];
        float w2 = W[(4 * k4 + 2) * 128 + j];
        float w3 = W[(4 * k4 + 3) * 128 + j];
        #pragma unroll
        for (int i = 0; i < 8; ++i) {
            float4 xv = *(const float4*)(&Xs[r0 + 2 * i][4 * k4]);
            acc[i] += xv.x * w0 + xv.y * w1 + xv.z * w2 + xv.w * w3;
        }
    }
    #pragma unroll
    for (int i = 0; i < 8; ++i) {
        int gr = block_row + r0 + 2 * i;
        if (gr < N) Hout[gr * 128 + j] = acc[i];
    }
}

// ---------------- attention logits: al_src/al_dst [N,2] ----------------

__global__ __launch_bounds__(256) void k_alpha(const float* __restrict__ Hm,
                                               const float* __restrict__ a_src,
                                               const float* __restrict__ a_dst,
                                               float* __restrict__ alsrc,
                                               float* __restrict__ aldst, int N) {
    int node = (int)((blockIdx.x * 256 + threadIdx.x) >> 6);
    int lane = threadIdx.x & 63;
    if (node >= N) return;
    float h0 = Hm[node * 128 + lane];
    float h1 = Hm[node * 128 + 64 + lane];
    float s0 = h0 * a_src[lane], s1 = h1 * a_src[64 + lane];
    float d0 = h0 * a_dst[lane], d1 = h1 * a_dst[64 + lane];
    #pragma unroll
    for (int o = 32; o > 0; o >>= 1) {
        s0 += __shfl_xor(s0, o); s1 += __shfl_xor(s1, o);
        d0 += __shfl_xor(d0, o); d1 += __shfl_xor(d1, o);
    }
    if (lane == 0) {
        alsrc[node * 2] = s0; alsrc[node * 2 + 1] = s1;
        aldst[node * 2] = d0; aldst[node * 2 + 1] = d1;
    }
}

// ---------------- softmax-aggregate per destination node (one wave64/node) ----------------

__global__ __launch_bounds__(256) void k_aggregate(
        const float* __restrict__ Hm,       // [N,128]
        const float* __restrict__ alsrc,    // [N,2]
        const float* __restrict__ aldst,    // [N,2]
        const int* __restrict__ off, const int* __restrict__ csr,
        const float* __restrict__ bias,     // [128]
        const float* __restrict__ prev,     // residual input or nullptr
        float* __restrict__ Out, int N, int mode) {
    int node = (int)((blockIdx.x * 256 + threadIdx.x) >> 6);
    int lane = threadIdx.x & 63;
    if (node >= N) return;
    int beg = off[node], end = off[node + 1];
    float ad0 = aldst[node * 2], ad1 = aldst[node * 2 + 1];

    // phase 1: segment max per head
    float m0 = -1e30f, m1 = -1e30f;
    for (int i = beg + lane; i < end; i += 64) {
        int s = csr[i];
        float e0 = alsrc[s * 2] + ad0;     e0 = e0 > 0.f ? e0 : LEAK * e0;
        float e1 = alsrc[s * 2 + 1] + ad1; e1 = e1 > 0.f ? e1 : LEAK * e1;
        m0 = fmaxf(m0, e0); m1 = fmaxf(m1, e1);
    }
    #pragma unroll
    for (int o = 32; o > 0; o >>= 1) {
        m0 = fmaxf(m0, __shfl_xor(m0, o));
        m1 = fmaxf(m1, __shfl_xor(m1, o));
    }

    // phase 2: weights + weighted feature sum
    // lane l owns flat channels 2l, 2l+1 (both in head l>>5)
    float accx = 0.f, accy = 0.f, dsum = 0.f;
    for (int base = beg; base < end; base += 64) {
        int i = base + lane;
        float w0 = 0.f, w1 = 0.f; int s = 0;
        if (i < end) {
            s = csr[i];
            float e0 = alsrc[s * 2] + ad0;     e0 = e0 > 0.f ? e0 : LEAK * e0;
            float e1 = alsrc[s * 2 + 1] + ad1; e1 = e1 > 0.f ? e1 : LEAK * e1;
            w0 = __expf(e0 - m0); w1 = __expf(e1 - m1);
        }
        int cntb = min(64, end - base);
        for (int jj = 0; jj < cntb; ++jj) {
            int   sj  = __shfl(s,  jj);
            float w0j = __shfl(w0, jj);
            float w1j = __shfl(w1, jj);
            float wsel = (lane < 32) ? w0j : w1j;
            float2 hv = *(const float2*)(&Hm[sj * 128 + lane * 2]);
            accx += wsel * hv.x;
            accy += wsel * hv.y;
            dsum += wsel;
        }
    }
    float inv = 1.f / dsum;
    int c0 = lane * 2;
    float v0 = accx * inv + bias[c0];
    float v1 = accy * inv + bias[c0 + 1];
    if (mode) { v0 += prev[node * 128 + c0]; v1 += prev[node * 128 + c0 + 1]; }
    v0 = v0 > 0.f ? v0 : LEAK * v0;
    v1 = v1 > 0.f ? v1 : LEAK * v1;
    *(float2*)(&Out[node * 128 + c0]) = make_float2(v0, v1);
}

// ---------------- final linear: logits = h3 @ lin_w + lin_b ----------------

__global__ __launch_bounds__(256) void k_final(const float* __restrict__ Hm,
                                               const float* __restrict__ lw,
                                               const float* __restrict__ lb,
                                               float* __restrict__ outp, int N) {
    int node = (int)((blockIdx.x * 256 + threadIdx.x) >> 6);
    int lane = threadIdx.x & 63;
    if (node >= N) return;
    float2 h = *(const float2*)(&Hm[node * 128 + lane * 2]);
    float2 w = *(const float2*)(&lw[lane * 2]);
    float v = h.x * w.x + h.y * w.y;
    #pragma unroll
    for (int o = 32; o > 0; o >>= 1) v += __shfl_xor(v, o);
    if (lane == 0) outp[node] = v + lb[0];
}

// ---------------- launch ----------------

extern "C" void kernel_launch(void* const* d_in, const int* in_sizes, int n_in,
                              void* d_out, int out_size, void* d_ws, size_t ws_size,
                              hipStream_t stream) {
    const float* x    = (const float*)d_in[0];
    const int*   edge = (const int*)d_in[1];
    const float* W[3]  = {(const float*)d_in[2], (const float*)d_in[6], (const float*)d_in[10]};
    const float* as[3] = {(const float*)d_in[3], (const float*)d_in[7], (const float*)d_in[11]};
    const float* ad[3] = {(const float*)d_in[4], (const float*)d_in[8], (const float*)d_in[12]};
    const float* bs[3] = {(const float*)d_in[5], (const float*)d_in[9], (const float*)d_in[13]};
    const float* lw = (const float*)d_in[14];
    const float* lb = (const float*)d_in[15];

    const int N    = in_sizes[0] / 128;
    const int E    = in_sizes[1] / 2;
    const int ETOT = E + N;

    // workspace carve-up (256B aligned)
    char* base = (char*)d_ws;
    size_t o = 0;
    auto carve = [&](size_t bytes) {
        char* p = base + o;
        o = (o + bytes + 255) & ~(size_t)255;
        return p;
    };
    int*   cnt   = (int*)  carve((size_t)N * 4);
    int*   off   = (int*)  carve((size_t)(N + 1) * 4);
    int*   boff  = (int*)  carve(64 * 4);
    int*   bsum  = (int*)  carve(64 * 4);
    int*   cur   = (int*)  carve((size_t)N * 4);
    int*   csr   = (int*)  carve((size_t)ETOT * 4);
    float* alsrc = (float*)carve((size_t)N * 2 * 4);
    float* aldst = (float*)carve((size_t)N * 2 * 4);
    float* hbuf  = (float*)carve((size_t)N * 128 * 4);
    float* bufA  = (float*)carve((size_t)N * 128 * 4);
    float* bufB  = (float*)carve((size_t)N * 128 * 4);
    (void)ws_size; (void)n_in; (void)out_size;

    const int* esrc = edge;
    const int* edst = edge + E;

    int nb = (N + 1023) / 1024;

    // CSR build
    hipMemsetAsync(cnt, 0, (size_t)N * 4, stream);
    k_hist<<<(ETOT + 255) / 256, 256, 0, stream>>>(edst, cnt, E, ETOT);
    k_scan1<<<nb, 1024, 0, stream>>>(cnt, off, bsum, N);
    k_scan2<<<1, 64, 0, stream>>>(bsum, boff, off, N, nb);
    k_scan3<<<nb, 1024, 0, stream>>>(off, boff, cur, N);
    k_scatter<<<(ETOT + 255) / 256, 256, 0, stream>>>(esrc, edst, cur, csr, E, ETOT);

    int gemm_blocks = (N + 15) / 16;
    int node_blocks = (N * 64 + 255) / 256;

    // layer 1: bufA = leaky(gat(x))
    k_gemm<<<gemm_blocks, 256, 0, stream>>>(x, W[0], hbuf, N);
    k_alpha<<<node_blocks, 256, 0, stream>>>(hbuf, as[0], ad[0], alsrc, aldst, N);
    k_aggregate<<<node_blocks, 256, 0, stream>>>(hbuf, alsrc, aldst, off, csr,
                                                 bs[0], nullptr, bufA, N, 0);
    // layer 2: bufB = leaky(bufA + gat(bufA))
    k_gemm<<<gemm_blocks, 256, 0, stream>>>(bufA, W[1], hbuf, N);
    k_alpha<<<node_blocks, 256, 0, stream>>>(hbuf, as[1], ad[1], alsrc, aldst, N);
    k_aggregate<<<node_blocks, 256, 0, stream>>>(hbuf, alsrc, aldst, off, csr,
                                                 bs[1], bufA, bufB, N, 1);
    // layer 3: bufA = leaky(bufB + gat(bufB))   (bufA reusable now)
    k_gemm<<<gemm_blocks, 256, 0, stream>>>(bufB, W[2], hbuf, N);
    k_alpha<<<node_blocks, 256, 0, stream>>>(hbuf, as[2], ad[2], alsrc, aldst, N);
    k_aggregate<<<node_blocks, 256, 0, stream>>>(hbuf, alsrc, aldst, off, csr,
                                                 bs[2], bufB, bufA, N, 1);

    // final linear
    k_final<<<node_blocks, 256, 0, stream>>>(bufA, lw, lb, (float*)d_out, N);
}

// Round 2
// 485.925 us; speedup vs baseline: 1.2628x; 1.2628x over previous
//
#include <hip/hip_runtime.h>
#include <hip/hip_bf16.h>
#include <hip/hip_fp16.h>

#define LEAK 0.2f

// ---------------- CSR build ----------------

__global__ __launch_bounds__(256) void k_hist(const int* __restrict__ edst,
                                              int* __restrict__ cnt, int E, int ETOT) {
    int e = blockIdx.x * 256 + threadIdx.x;
    if (e >= ETOT) return;
    int d = (e < E) ? edst[e] : (e - E);
    atomicAdd(&cnt[d], 1);
}

__global__ __launch_bounds__(1024) void k_scan1(const int* __restrict__ cnt,
                                                int* __restrict__ off,
                                                int* __restrict__ bsum, int N) {
    int i = blockIdx.x * 1024 + threadIdx.x;
    int v = (i < N) ? cnt[i] : 0;
    int lane = threadIdx.x & 63, wid = threadIdx.x >> 6;
    int x = v;
    #pragma unroll
    for (int o = 1; o < 64; o <<= 1) {
        int y = __shfl_up(x, o);
        if (lane >= o) x += y;
    }
    __shared__ int wsum[16];
    if (lane == 63) wsum[wid] = x;
    __syncthreads();
    if (wid == 0) {
        int s = (lane < 16) ? wsum[lane] : 0;
        #pragma unroll
        for (int o = 1; o < 16; o <<= 1) {
            int y = __shfl_up(s, o);
            if (lane >= o) s += y;
        }
        if (lane < 16) wsum[lane] = s;   // inclusive wave sums
    }
    __syncthreads();
    int waveoff = (wid > 0) ? wsum[wid - 1] : 0;
    int incl = x + waveoff;
    if (i < N) off[i] = incl - v;        // exclusive within block
    if (threadIdx.x == 1023) bsum[blockIdx.x] = incl;
}

__global__ void k_scan2(const int* __restrict__ bsum, int* __restrict__ boff,
                        int* __restrict__ off, int N, int nb) {
    int lane = threadIdx.x;   // 64 threads
    int v = (lane < nb) ? bsum[lane] : 0;
    int x = v;
    #pragma unroll
    for (int o = 1; o < 64; o <<= 1) {
        int y = __shfl_up(x, o);
        if (lane >= o) x += y;
    }
    if (lane < nb) boff[lane] = x - v;   // exclusive
    if (lane == 63) off[N] = x;          // grand total
}

__global__ __launch_bounds__(1024) void k_scan3(int* __restrict__ off,
                                                const int* __restrict__ boff,
                                                int* __restrict__ cur, int N) {
    int i = blockIdx.x * 1024 + threadIdx.x;
    if (i >= N) return;
    int o = off[i] + boff[blockIdx.x];
    off[i] = o;
    cur[i] = o;
}

__global__ __launch_bounds__(256) void k_scatter(const int* __restrict__ esrc,
                                                 const int* __restrict__ edst,
                                                 int* __restrict__ cur,
                                                 int* __restrict__ csr, int E, int ETOT) {
    int e = blockIdx.x * 256 + threadIdx.x;
    if (e >= ETOT) return;
    int s, d;
    if (e < E) { s = esrc[e]; d = edst[e]; } else { s = d = e - E; }
    int pos = atomicAdd(&cur[d], 1);
    csr[pos] = s;
}

// ---------------- GEMM: h16 = fp16(X @ W)   (X:[N,128] fp32, W:[128,128] fp32) ----------------

__global__ __launch_bounds__(256) void k_gemm(const float* __restrict__ X,
                                              const float* __restrict__ W,
                                              __half* __restrict__ Hout, int N) {
    __shared__ float Xs[16][128];
    int block_row = blockIdx.x * 16;
    int t = threadIdx.x;
    for (int i = t; i < 16 * 128; i += 256) {
        int r = i >> 7, c = i & 127;
        int gr = block_row + r;
        Xs[r][c] = (gr < N) ? X[gr * 128 + c] : 0.f;
    }
    __syncthreads();
    int j = t & 127;     // output column
    int r0 = t >> 7;     // 0 or 1; thread covers rows r0, r0+2, ..., r0+14
    float acc[8];
    #pragma unroll
    for (int i = 0; i < 8; ++i) acc[i] = 0.f;
    for (int k4 = 0; k4 < 32; ++k4) {
        float w0 = W[(4 * k4 + 0) * 128 + j];
        float w1 = W[(4 * k4 + 1) * 128 + j];
        float w2 = W[(4 * k4 + 2) * 128 + j];
        float w3 = W[(4 * k4 + 3) * 128 + j];
        #pragma unroll
        for (int i = 0; i < 8; ++i) {
            float4 xv = *(const float4*)(&Xs[r0 + 2 * i][4 * k4]);
            acc[i] += xv.x * w0 + xv.y * w1 + xv.z * w2 + xv.w * w3;
        }
    }
    #pragma unroll
    for (int i = 0; i < 8; ++i) {
        int gr = block_row + r0 + 2 * i;
        if (gr < N) Hout[(size_t)gr * 128 + j] = __float2half(acc[i]);
    }
}

// ---------------- attention logits: al_src/al_dst [N,2] ----------------

__global__ __launch_bounds__(256) void k_alpha(const __half* __restrict__ H16,
                                               const float* __restrict__ a_src,
                                               const float* __restrict__ a_dst,
                                               float* __restrict__ alsrc,
                                               float* __restrict__ aldst, int N) {
    int node = (int)((blockIdx.x * 256 + threadIdx.x) >> 6);
    int lane = threadIdx.x & 63;
    if (node >= N) return;
    float2 h = __half22float2(*(const __half2*)(H16 + (size_t)node * 128 + 2 * lane));
    int c = 2 * lane;   // lanes 0..31 -> head 0 channels, 32..63 -> head 1
    float s = h.x * a_src[c] + h.y * a_src[c + 1];
    float d = h.x * a_dst[c] + h.y * a_dst[c + 1];
    #pragma unroll
    for (int o = 1; o < 32; o <<= 1) { s += __shfl_xor(s, o); d += __shfl_xor(d, o); }
    if (lane == 0)  { alsrc[node * 2]     = s; aldst[node * 2]     = d; }
    if (lane == 32) { alsrc[node * 2 + 1] = s; aldst[node * 2 + 1] = d; }
}

// ---------------- softmax-aggregate: one wave64 per dst node, 4 edges/iter ----------------
// No segment-max pass: logits are bounded (|e| < ~30), exp() is safe in fp32 and
// softmax is shift-invariant, so the result matches the max-subtracted reference.

__global__ __launch_bounds__(256) void k_aggregate(
        const __half* __restrict__ H16,     // [N,128] fp16
        const float* __restrict__ alsrc,    // [N,2]
        const float* __restrict__ aldst,    // [N,2]
        const int* __restrict__ off, const int* __restrict__ csr,
        const float* __restrict__ bias,     // [128]
        const float* __restrict__ prev,     // residual input or nullptr
        float* __restrict__ Out, int N, int mode) {
    int node = (int)((blockIdx.x * 256 + threadIdx.x) >> 6);
    int lane = threadIdx.x & 63;
    if (node >= N) return;
    int beg = off[node], end = off[node + 1];
    float ad0 = aldst[node * 2], ad1 = aldst[node * 2 + 1];

    int p = lane & 15;          // channel group: this lane accumulates channels [8p, 8p+8)
    int q = lane >> 4;          // edge subgroup: this lane processes edges == q (mod 4)
    bool head0 = p < 8;

    float acc[8];
    #pragma unroll
    for (int i = 0; i < 8; ++i) acc[i] = 0.f;
    float dsum = 0.f;

    for (int base = beg; base < end; base += 64) {
        int i = base + lane;
        float w0 = 0.f, w1 = 0.f; int s = 0;
        if (i < end) {
            s = csr[i];
            float2 al = *(const float2*)(&alsrc[s * 2]);
            float e0 = al.x + ad0; e0 = e0 > 0.f ? e0 : LEAK * e0;
            float e1 = al.y + ad1; e1 = e1 > 0.f ? e1 : LEAK * e1;
            w0 = __expf(e0); w1 = __expf(e1);
        }
        int cnt = min(64, end - base);
        int iters = (cnt + 3) >> 2;
        for (int jj = 0; jj < iters; ++jj) {
            int sl = (jj << 2) + q;           // lane holding this edge's (s, w)
            int   sj  = __shfl(s,  sl);
            float w0j = __shfl(w0, sl);
            float w1j = __shfl(w1, sl);
            float wsel = head0 ? w0j : w1j;   // 0 for tail slots -> harmless
            const __half2* hp = (const __half2*)(H16 + (size_t)sj * 128 + p * 8);
            uint4 raw = *(const uint4*)hp;    // 8 fp16 = 16 B
            const __half2* hh = (const __half2*)&raw;
            #pragma unroll
            for (int tt = 0; tt < 4; ++tt) {
                float2 f = __half22float2(hh[tt]);
                acc[2 * tt]     += wsel * f.x;
                acc[2 * tt + 1] += wsel * f.y;
            }
            dsum += wsel;
        }
    }

    // sum the 4 edge-subgroups together
    #pragma unroll
    for (int i = 0; i < 8; ++i) {
        acc[i] += __shfl_xor(acc[i], 16);
        acc[i] += __shfl_xor(acc[i], 32);
    }
    dsum += __shfl_xor(dsum, 16);
    dsum += __shfl_xor(dsum, 32);

    if (q == 0) {
        float inv = 1.f / dsum;
        int c0 = p * 8;
        float v[8];
        #pragma unroll
        for (int i = 0; i < 8; ++i) v[i] = acc[i] * inv + bias[c0 + i];
        if (mode) {
            float4 p0 = *(const float4*)(&prev[(size_t)node * 128 + c0]);
            float4 p1 = *(const float4*)(&prev[(size_t)node * 128 + c0 + 4]);
            v[0] += p0.x; v[1] += p0.y; v[2] += p0.z; v[3] += p0.w;
            v[4] += p1.x; v[5] += p1.y; v[6] += p1.z; v[7] += p1.w;
        }
        #pragma unroll
        for (int i = 0; i < 8; ++i) v[i] = v[i] > 0.f ? v[i] : LEAK * v[i];
        *(float4*)(&Out[(size_t)node * 128 + c0])     = make_float4(v[0], v[1], v[2], v[3]);
        *(float4*)(&Out[(size_t)node * 128 + c0 + 4]) = make_float4(v[4], v[5], v[6], v[7]);
    }
}

// ---------------- final linear: logits = h3 @ lin_w + lin_b ----------------

__global__ __launch_bounds__(256) void k_final(const float* __restrict__ Hm,
                                               const float* __restrict__ lw,
                                               const float* __restrict__ lb,
                                               float* __restrict__ outp, int N) {
    int node = (int)((blockIdx.x * 256 + threadIdx.x) >> 6);
    int lane = threadIdx.x & 63;
    if (node >= N) return;
    float2 h = *(const float2*)(&Hm[(size_t)node * 128 + lane * 2]);
    float2 w = *(const float2*)(&lw[lane * 2]);
    float v = h.x * w.x + h.y * w.y;
    #pragma unroll
    for (int o = 32; o > 0; o >>= 1) v += __shfl_xor(v, o);
    if (lane == 0) outp[node] = v + lb[0];
}

// ---------------- launch ----------------

extern "C" void kernel_launch(void* const* d_in, const int* in_sizes, int n_in,
                              void* d_out, int out_size, void* d_ws, size_t ws_size,
                              hipStream_t stream) {
    const float* x    = (const float*)d_in[0];
    const int*   edge = (const int*)d_in[1];
    const float* W[3]  = {(const float*)d_in[2], (const float*)d_in[6], (const float*)d_in[10]};
    const float* as[3] = {(const float*)d_in[3], (const float*)d_in[7], (const float*)d_in[11]};
    const float* ad[3] = {(const float*)d_in[4], (const float*)d_in[8], (const float*)d_in[12]};
    const float* bs[3] = {(const float*)d_in[5], (const float*)d_in[9], (const float*)d_in[13]};
    const float* lw = (const float*)d_in[14];
    const float* lb = (const float*)d_in[15];

    const int N    = in_sizes[0] / 128;
    const int E    = in_sizes[1] / 2;
    const int ETOT = E + N;

    // workspace carve-up (256B aligned)
    char* base = (char*)d_ws;
    size_t o = 0;
    auto carve = [&](size_t bytes) {
        char* p = base + o;
        o = (o + bytes + 255) & ~(size_t)255;
        return p;
    };
    int*    cnt   = (int*)   carve((size_t)N * 4);
    int*    off   = (int*)   carve((size_t)(N + 1) * 4);
    int*    boff  = (int*)   carve(64 * 4);
    int*    bsum  = (int*)   carve(64 * 4);
    int*    cur   = (int*)   carve((size_t)N * 4);
    int*    csr   = (int*)   carve((size_t)ETOT * 4);
    float*  alsrc = (float*) carve((size_t)N * 2 * 4);
    float*  aldst = (float*) carve((size_t)N * 2 * 4);
    __half* h16   = (__half*)carve((size_t)N * 128 * 2);
    float*  bufA  = (float*) carve((size_t)N * 128 * 4);
    float*  bufB  = (float*) carve((size_t)N * 128 * 4);
    (void)ws_size; (void)n_in; (void)out_size;

    const int* esrc = edge;
    const int* edst = edge + E;

    int nb = (N + 1023) / 1024;

    // CSR build
    hipMemsetAsync(cnt, 0, (size_t)N * 4, stream);
    k_hist<<<(ETOT + 255) / 256, 256, 0, stream>>>(edst, cnt, E, ETOT);
    k_scan1<<<nb, 1024, 0, stream>>>(cnt, off, bsum, N);
    k_scan2<<<1, 64, 0, stream>>>(bsum, boff, off, N, nb);
    k_scan3<<<nb, 1024, 0, stream>>>(off, boff, cur, N);
    k_scatter<<<(ETOT + 255) / 256, 256, 0, stream>>>(esrc, edst, cur, csr, E, ETOT);

    int gemm_blocks = (N + 15) / 16;
    int node_blocks = (N * 64 + 255) / 256;

    // layer 1: bufA = leaky(gat(x))
    k_gemm<<<gemm_blocks, 256, 0, stream>>>(x, W[0], h16, N);
    k_alpha<<<node_blocks, 256, 0, stream>>>(h16, as[0], ad[0], alsrc, aldst, N);
    k_aggregate<<<node_blocks, 256, 0, stream>>>(h16, alsrc, aldst, off, csr,
                                                 bs[0], nullptr, bufA, N, 0);
    // layer 2: bufB = leaky(bufA + gat(bufA))
    k_gemm<<<gemm_blocks, 256, 0, stream>>>(bufA, W[1], h16, N);
    k_alpha<<<node_blocks, 256, 0, stream>>>(h16, as[1], ad[1], alsrc, aldst, N);
    k_aggregate<<<node_blocks, 256, 0, stream>>>(h16, alsrc, aldst, off, csr,
                                                 bs[1], bufA, bufB, N, 1);
    // layer 3: bufA = leaky(bufB + gat(bufB))
    k_gemm<<<gemm_blocks, 256, 0, stream>>>(bufB, W[2], h16, N);
    k_alpha<<<node_blocks, 256, 0, stream>>>(h16, as[2], ad[2], alsrc, aldst, N);
    k_aggregate<<<node_blocks, 256, 0, stream>>>(h16, alsrc, aldst, off, csr,
                                                 bs[2], bufB, bufA, N, 1);

    // final linear
    k_final<<<node_blocks, 256, 0, stream>>>(bufA, lw, lb, (float*)d_out, N);
}

// Round 3
// 376.863 us; speedup vs baseline: 1.6283x; 1.2894x over previous
//
#include <hip/hip_runtime.h>
#include <hip/hip_bf16.h>
#include <hip/hip_fp16.h>

#define LEAK 0.2f

typedef _Float16 half8  __attribute__((ext_vector_type(8)));
typedef _Float16 half4v __attribute__((ext_vector_type(4)));
typedef float    float4v __attribute__((ext_vector_type(4)));

// ---------------- CSR build ----------------

__global__ __launch_bounds__(256) void k_hist(const int* __restrict__ edst,
                                              int* __restrict__ cnt, int E, int ETOT) {
    int e0 = blockIdx.x * 512 + threadIdx.x;
    #pragma unroll
    for (int u = 0; u < 2; ++u) {
        int e = e0 + u * 256;
        if (e < ETOT) {
            int d = (e < E) ? edst[e] : (e - E);
            atomicAdd(&cnt[d], 1);
        }
    }
}

__global__ __launch_bounds__(1024) void k_scan1(const int* __restrict__ cnt,
                                                int* __restrict__ off,
                                                int* __restrict__ bsum, int N) {
    int i = blockIdx.x * 1024 + threadIdx.x;
    int v = (i < N) ? cnt[i] : 0;
    int lane = threadIdx.x & 63, wid = threadIdx.x >> 6;
    int x = v;
    #pragma unroll
    for (int o = 1; o < 64; o <<= 1) {
        int y = __shfl_up(x, o);
        if (lane >= o) x += y;
    }
    __shared__ int wsum[16];
    if (lane == 63) wsum[wid] = x;
    __syncthreads();
    if (wid == 0) {
        int s = (lane < 16) ? wsum[lane] : 0;
        #pragma unroll
        for (int o = 1; o < 16; o <<= 1) {
            int y = __shfl_up(s, o);
            if (lane >= o) s += y;
        }
        if (lane < 16) wsum[lane] = s;   // inclusive wave sums
    }
    __syncthreads();
    int waveoff = (wid > 0) ? wsum[wid - 1] : 0;
    int incl = x + waveoff;
    if (i < N) off[i] = incl - v;        // exclusive within block
    if (threadIdx.x == 1023) bsum[blockIdx.x] = incl;
}

__global__ void k_scan2(const int* __restrict__ bsum, int* __restrict__ boff,
                        int* __restrict__ off, int N, int nb) {
    int lane = threadIdx.x;   // 64 threads
    int v = (lane < nb) ? bsum[lane] : 0;
    int x = v;
    #pragma unroll
    for (int o = 1; o < 64; o <<= 1) {
        int y = __shfl_up(x, o);
        if (lane >= o) x += y;
    }
    if (lane < nb) boff[lane] = x - v;   // exclusive
    if (lane == 63) off[N] = x;          // grand total
}

__global__ __launch_bounds__(1024) void k_scan3(int* __restrict__ off,
                                                const int* __restrict__ boff,
                                                int* __restrict__ cur, int N) {
    int i = blockIdx.x * 1024 + threadIdx.x;
    if (i >= N) return;
    int o = off[i] + boff[blockIdx.x];
    off[i] = o;
    cur[i] = o;
}

__global__ __launch_bounds__(256) void k_scatter(const int* __restrict__ esrc,
                                                 const int* __restrict__ edst,
                                                 int* __restrict__ cur,
                                                 int* __restrict__ csr, int E, int ETOT) {
    int e0 = blockIdx.x * 512 + threadIdx.x;
    #pragma unroll
    for (int u = 0; u < 2; ++u) {
        int e = e0 + u * 256;
        if (e < ETOT) {
            int s, d;
            if (e < E) { s = esrc[e]; d = edst[e]; } else { s = d = e - E; }
            int pos = atomicAdd(&cur[d], 1);
            csr[pos] = s;
        }
    }
}

// ---------------- W -> fp16 conversion (once per call) ----------------

__global__ __launch_bounds__(256) void k_wconv(const float* __restrict__ W0,
                                               const float* __restrict__ W1,
                                               const float* __restrict__ W2,
                                               _Float16* __restrict__ w16) {
    int i = blockIdx.x * 256 + threadIdx.x;
    if (i >= 3 * 16384) return;
    const float* src = (i < 16384) ? W0 : (i < 32768 ? W1 : W2);
    w16[i] = (_Float16)src[i & 16383];
}

// ---------------- MFMA fp16 GEMM: h16 = fp16(X @ W)  (X:[N,128] fp32, Wh:[128,128] fp16) ----
// 16x16x32_f16 lane maps (m89-verified, dtype-independent):
//   A[m][k]: m = lane&15, k = (lane>>4)*8 + j   (j = reg element 0..7)
//   B[k][n]: n = lane&15, k = (lane>>4)*8 + j
//   C/D[r][c]: c = lane&15, r = (lane>>4)*4 + reg

__global__ __launch_bounds__(256) void k_gemm_mfma(const float* __restrict__ X,
                                                   const _Float16* __restrict__ Wh,
                                                   __half* __restrict__ Hout, int N) {
    __shared__ _Float16 As[64][136];   // +8 halves pad -> only 2-way bank aliasing (free)
    const int t = threadIdx.x;
    const int lane = t & 63, w = t >> 6;
    const int block_row = blockIdx.x * 64;

    // stage X (fp32) -> As (fp16)
    #pragma unroll
    for (int it = 0; it < 8; ++it) {
        int i = t + 256 * it;
        int row = i >> 5, c4 = i & 31;
        int gr = block_row + row;
        float4 xv = make_float4(0.f, 0.f, 0.f, 0.f);
        if (gr < N) xv = *(const float4*)(X + (size_t)gr * 128 + c4 * 4);
        half4v hv;
        hv[0] = (_Float16)xv.x; hv[1] = (_Float16)xv.y;
        hv[2] = (_Float16)xv.z; hv[3] = (_Float16)xv.w;
        *(half4v*)(&As[row][c4 * 4]) = hv;
    }

    // preload this wave's B fragments (W16 is 32 KB, L1/L2-resident; once per block)
    const int l15 = lane & 15, kq = (lane >> 4) * 8;
    half8 bf[2][4];
    #pragma unroll
    for (int ntl = 0; ntl < 2; ++ntl) {
        int n0 = (w * 2 + ntl) * 16 + l15;
        #pragma unroll
        for (int kt = 0; kt < 4; ++kt)
            #pragma unroll
            for (int j = 0; j < 8; ++j)
                bf[ntl][kt][j] = Wh[(kt * 32 + kq + j) * 128 + n0];
    }
    __syncthreads();

    float4v acc[4][2];
    #pragma unroll
    for (int mt = 0; mt < 4; ++mt)
        #pragma unroll
        for (int ntl = 0; ntl < 2; ++ntl)
            acc[mt][ntl] = (float4v){0.f, 0.f, 0.f, 0.f};

    #pragma unroll
    for (int kt = 0; kt < 4; ++kt) {
        half8 a[4];
        #pragma unroll
        for (int mt = 0; mt < 4; ++mt)
            a[mt] = *(const half8*)(&As[mt * 16 + l15][kt * 32 + kq]);
        #pragma unroll
        for (int mt = 0; mt < 4; ++mt)
            #pragma unroll
            for (int ntl = 0; ntl < 2; ++ntl)
                acc[mt][ntl] = __builtin_amdgcn_mfma_f32_16x16x32_f16(
                    a[mt], bf[ntl][kt], acc[mt][ntl], 0, 0, 0);
    }

    // epilogue: fp32 acc -> fp16 h
    #pragma unroll
    for (int mt = 0; mt < 4; ++mt) {
        int r0 = block_row + mt * 16 + (lane >> 4) * 4;
        #pragma unroll
        for (int ntl = 0; ntl < 2; ++ntl) {
            int col = (w * 2 + ntl) * 16 + l15;
            #pragma unroll
            for (int reg = 0; reg < 4; ++reg) {
                int r = r0 + reg;
                if (r < N) Hout[(size_t)r * 128 + col] = __float2half((float)acc[mt][ntl][reg]);
            }
        }
    }
}

// ---------------- attention logits: al_src/al_dst [N,2] ----------------

__global__ __launch_bounds__(256) void k_alpha(const __half* __restrict__ H16,
                                               const float* __restrict__ a_src,
                                               const float* __restrict__ a_dst,
                                               float* __restrict__ alsrc,
                                               float* __restrict__ aldst, int N) {
    int node = (int)((blockIdx.x * 256 + threadIdx.x) >> 6);
    int lane = threadIdx.x & 63;
    if (node >= N) return;
    float2 h = __half22float2(*(const __half2*)(H16 + (size_t)node * 128 + 2 * lane));
    int c = 2 * lane;   // lanes 0..31 -> head 0 channels, 32..63 -> head 1
    float s = h.x * a_src[c] + h.y * a_src[c + 1];
    float d = h.x * a_dst[c] + h.y * a_dst[c + 1];
    #pragma unroll
    for (int o = 1; o < 32; o <<= 1) { s += __shfl_xor(s, o); d += __shfl_xor(d, o); }
    if (lane == 0)  { alsrc[node * 2]     = s; aldst[node * 2]     = d; }
    if (lane == 32) { alsrc[node * 2 + 1] = s; aldst[node * 2 + 1] = d; }
}

// ---------------- softmax-aggregate: one wave64 per dst node, 4 edges/iter ----------------
// No segment-max pass: logits are bounded, exp() safe in fp32; softmax shift-invariant.

__global__ __launch_bounds__(256) void k_aggregate(
        const __half* __restrict__ H16,     // [N,128] fp16
        const float* __restrict__ alsrc,    // [N,2]
        const float* __restrict__ aldst,    // [N,2]
        const int* __restrict__ off, const int* __restrict__ csr,
        const float* __restrict__ bias,     // [128]
        const float* __restrict__ prev,     // residual input or nullptr
        float* __restrict__ Out, int N, int mode) {
    int node = (int)((blockIdx.x * 256 + threadIdx.x) >> 6);
    int lane = threadIdx.x & 63;
    if (node >= N) return;
    int beg = off[node], end = off[node + 1];
    float ad0 = aldst[node * 2], ad1 = aldst[node * 2 + 1];

    int p = lane & 15;          // channel group: accumulates channels [8p, 8p+8)
    int q = lane >> 4;          // edge subgroup: processes edges == q (mod 4)
    bool head0 = p < 8;

    float acc[8];
    #pragma unroll
    for (int i = 0; i < 8; ++i) acc[i] = 0.f;
    float dsum = 0.f;

    for (int base = beg; base < end; base += 64) {
        int i = base + lane;
        float w0 = 0.f, w1 = 0.f; int s = 0;
        if (i < end) {
            s = csr[i];
            float2 al = *(const float2*)(&alsrc[s * 2]);
            float e0 = al.x + ad0; e0 = e0 > 0.f ? e0 : LEAK * e0;
            float e1 = al.y + ad1; e1 = e1 > 0.f ? e1 : LEAK * e1;
            w0 = __expf(e0); w1 = __expf(e1);
        }
        int cnt = min(64, end - base);
        int iters = (cnt + 3) >> 2;
        for (int jj = 0; jj < iters; ++jj) {
            int sl = (jj << 2) + q;           // lane holding this edge's (s, w)
            int   sj  = __shfl(s,  sl);
            float w0j = __shfl(w0, sl);
            float w1j = __shfl(w1, sl);
            float wsel = head0 ? w0j : w1j;   // 0 for tail slots -> harmless
            const __half2* hp = (const __half2*)(H16 + (size_t)sj * 128 + p * 8);
            uint4 raw = *(const uint4*)hp;    // 8 fp16 = 16 B
            const __half2* hh = (const __half2*)&raw;
            #pragma unroll
            for (int tt = 0; tt < 4; ++tt) {
                float2 f = __half22float2(hh[tt]);
                acc[2 * tt]     += wsel * f.x;
                acc[2 * tt + 1] += wsel * f.y;
            }
            dsum += wsel;
        }
    }

    #pragma unroll
    for (int i = 0; i < 8; ++i) {
        acc[i] += __shfl_xor(acc[i], 16);
        acc[i] += __shfl_xor(acc[i], 32);
    }
    dsum += __shfl_xor(dsum, 16);
    dsum += __shfl_xor(dsum, 32);

    if (q == 0) {
        float inv = 1.f / dsum;
        int c0 = p * 8;
        float v[8];
        #pragma unroll
        for (int i = 0; i < 8; ++i) v[i] = acc[i] * inv + bias[c0 + i];
        if (mode) {
            float4 p0 = *(const float4*)(&prev[(size_t)node * 128 + c0]);
            float4 p1 = *(const float4*)(&prev[(size_t)node * 128 + c0 + 4]);
            v[0] += p0.x; v[1] += p0.y; v[2] += p0.z; v[3] += p0.w;
            v[4] += p1.x; v[5] += p1.y; v[6] += p1.z; v[7] += p1.w;
        }
        #pragma unroll
        for (int i = 0; i < 8; ++i) v[i] = v[i] > 0.f ? v[i] : LEAK * v[i];
        *(float4*)(&Out[(size_t)node * 128 + c0])     = make_float4(v[0], v[1], v[2], v[3]);
        *(float4*)(&Out[(size_t)node * 128 + c0 + 4]) = make_float4(v[4], v[5], v[6], v[7]);
    }
}

// ---------------- final linear ----------------

__global__ __launch_bounds__(256) void k_final(const float* __restrict__ Hm,
                                               const float* __restrict__ lw,
                                               const float* __restrict__ lb,
                                               float* __restrict__ outp, int N) {
    int node = (int)((blockIdx.x * 256 + threadIdx.x) >> 6);
    int lane = threadIdx.x & 63;
    if (node >= N) return;
    float2 h = *(const float2*)(&Hm[(size_t)node * 128 + lane * 2]);
    float2 w = *(const float2*)(&lw[lane * 2]);
    float v = h.x * w.x + h.y * w.y;
    #pragma unroll
    for (int o = 32; o > 0; o >>= 1) v += __shfl_xor(v, o);
    if (lane == 0) outp[node] = v + lb[0];
}

// ---------------- launch ----------------

extern "C" void kernel_launch(void* const* d_in, const int* in_sizes, int n_in,
                              void* d_out, int out_size, void* d_ws, size_t ws_size,
                              hipStream_t stream) {
    const float* x    = (const float*)d_in[0];
    const int*   edge = (const int*)d_in[1];
    const float* W[3]  = {(const float*)d_in[2], (const float*)d_in[6], (const float*)d_in[10]};
    const float* as[3] = {(const float*)d_in[3], (const float*)d_in[7], (const float*)d_in[11]};
    const float* ad[3] = {(const float*)d_in[4], (const float*)d_in[8], (const float*)d_in[12]};
    const float* bs[3] = {(const float*)d_in[5], (const float*)d_in[9], (const float*)d_in[13]};
    const float* lw = (const float*)d_in[14];
    const float* lb = (const float*)d_in[15];

    const int N    = in_sizes[0] / 128;
    const int E    = in_sizes[1] / 2;
    const int ETOT = E + N;

    char* base = (char*)d_ws;
    size_t o = 0;
    auto carve = [&](size_t bytes) {
        char* p = base + o;
        o = (o + bytes + 255) & ~(size_t)255;
        return p;
    };
    int*      cnt   = (int*)     carve((size_t)N * 4);
    int*      off   = (int*)     carve((size_t)(N + 1) * 4);
    int*      boff  = (int*)     carve(64 * 4);
    int*      bsum  = (int*)     carve(64 * 4);
    int*      cur   = (int*)     carve((size_t)N * 4);
    int*      csr   = (int*)     carve((size_t)ETOT * 4);
    float*    alsrc = (float*)   carve((size_t)N * 2 * 4);
    float*    aldst = (float*)   carve((size_t)N * 2 * 4);
    __half*   h16   = (__half*)  carve((size_t)N * 128 * 2);
    float*    bufA  = (float*)   carve((size_t)N * 128 * 4);
    float*    bufB  = (float*)   carve((size_t)N * 128 * 4);
    _Float16* w16   = (_Float16*)carve((size_t)3 * 16384 * 2);
    (void)ws_size; (void)n_in; (void)out_size;

    const int* esrc = edge;
    const int* edst = edge + E;

    int nb = (N + 1023) / 1024;

    // CSR build + W conversion (independent streams of work, same queue)
    hipMemsetAsync(cnt, 0, (size_t)N * 4, stream);
    k_wconv<<<192, 256, 0, stream>>>(W[0], W[1], W[2], w16);
    k_hist<<<(ETOT + 511) / 512, 256, 0, stream>>>(edst, cnt, E, ETOT);
    k_scan1<<<nb, 1024, 0, stream>>>(cnt, off, bsum, N);
    k_scan2<<<1, 64, 0, stream>>>(bsum, boff, off, N, nb);
    k_scan3<<<nb, 1024, 0, stream>>>(off, boff, cur, N);
    k_scatter<<<(ETOT + 511) / 512, 256, 0, stream>>>(esrc, edst, cur, csr, E, ETOT);

    int gemm_blocks = (N + 63) / 64;
    int node_blocks = (N * 64 + 255) / 256;

    // layer 1: bufA = leaky(gat(x))
    k_gemm_mfma<<<gemm_blocks, 256, 0, stream>>>(x, w16, h16, N);
    k_alpha<<<node_blocks, 256, 0, stream>>>(h16, as[0], ad[0], alsrc, aldst, N);
    k_aggregate<<<node_blocks, 256, 0, stream>>>(h16, alsrc, aldst, off, csr,
                                                 bs[0], nullptr, bufA, N, 0);
    // layer 2: bufB = leaky(bufA + gat(bufA))
    k_gemm_mfma<<<gemm_blocks, 256, 0, stream>>>(bufA, w16 + 16384, h16, N);
    k_alpha<<<node_blocks, 256, 0, stream>>>(h16, as[1], ad[1], alsrc, aldst, N);
    k_aggregate<<<node_blocks, 256, 0, stream>>>(h16, alsrc, aldst, off, csr,
                                                 bs[1], bufA, bufB, N, 1);
    // layer 3: bufA = leaky(bufB + gat(bufB))
    k_gemm_mfma<<<gemm_blocks, 256, 0, stream>>>(bufB, w16 + 32768, h16, N);
    k_alpha<<<node_blocks, 256, 0, stream>>>(h16, as[2], ad[2], alsrc, aldst, N);
    k_aggregate<<<node_blocks, 256, 0, stream>>>(h16, alsrc, aldst, off, csr,
                                                 bs[2], bufB, bufA, N, 1);

    // final linear
    k_final<<<node_blocks, 256, 0, stream>>>(bufA, lw, lb, (float*)d_out, N);
}

// Round 4
// 327.788 us; speedup vs baseline: 1.8721x; 1.1497x over previous
//
#include <hip/hip_runtime.h>
#include <hip/hip_bf16.h>
#include <hip/hip_fp16.h>

#define LEAK 0.2f

typedef _Float16 half8  __attribute__((ext_vector_type(8)));
typedef _Float16 half4v __attribute__((ext_vector_type(4)));
typedef float    float4v __attribute__((ext_vector_type(4)));

// ================= bucketed CSR build =================
// bucket b = dst >> 7 (128 nodes per bucket). NBK <= 512 (N <= 65536).
// packed edge word: src | (dloc << 17)  (src < 2^17, dloc < 128)

__global__ __launch_bounds__(256) void k_bincount(const int* __restrict__ edst,
                                                  int* __restrict__ gbkt,
                                                  int E, int ETOT, int NBK) {
    __shared__ int lh[512];
    int t = threadIdx.x;
    for (int b = t; b < NBK; b += 256) lh[b] = 0;
    __syncthreads();
    int base = blockIdx.x * 4096;
    #pragma unroll
    for (int u = 0; u < 16; ++u) {
        int e = base + u * 256 + t;
        if (e < ETOT) {
            int d = (e < E) ? edst[e] : (e - E);
            atomicAdd(&lh[d >> 7], 1);
        }
    }
    __syncthreads();
    for (int b = t; b < NBK; b += 256)
        if (lh[b]) atomicAdd(&gbkt[b], lh[b]);
}

__global__ __launch_bounds__(512) void k_bktscan(const int* __restrict__ gbkt,
                                                 int* __restrict__ bko,
                                                 int* __restrict__ gcur, int NBK) {
    int t = threadIdx.x;
    int v = (t < NBK) ? gbkt[t] : 0;
    int lane = t & 63, wid = t >> 6;
    int x = v;
    #pragma unroll
    for (int o = 1; o < 64; o <<= 1) {
        int y = __shfl_up(x, o);
        if (lane >= o) x += y;
    }
    __shared__ int ws[8];
    if (lane == 63) ws[wid] = x;
    __syncthreads();
    if (wid == 0) {
        int s = (lane < 8) ? ws[lane] : 0;
        #pragma unroll
        for (int o = 1; o < 8; o <<= 1) {
            int y = __shfl_up(s, o);
            if (lane >= o) s += y;
        }
        if (lane < 8) ws[lane] = s;
    }
    __syncthreads();
    int excl = x - v + (wid > 0 ? ws[wid - 1] : 0);
    if (t < NBK) { bko[t] = excl; gcur[t] = excl; }
    if (t == 511) bko[NBK] = excl;   // v==0 here -> excl == grand total
}

__global__ __launch_bounds__(256) void k_binscatter(const int* __restrict__ esrc,
                                                    const int* __restrict__ edst,
                                                    int* __restrict__ gcur,
                                                    unsigned int* __restrict__ binned,
                                                    int E, int ETOT, int NBK) {
    __shared__ int lh[512];
    __shared__ int lbase[512];
    int t = threadIdx.x;
    for (int b = t; b < NBK; b += 256) lh[b] = 0;
    __syncthreads();
    int base = blockIdx.x * 4096;
    unsigned int word[16]; int bb[16], rk[16];
    #pragma unroll
    for (int u = 0; u < 16; ++u) {
        int e = base + u * 256 + t;
        bb[u] = -1;
        if (e < ETOT) {
            int s, d;
            if (e < E) { s = esrc[e]; d = edst[e]; } else { s = d = e - E; }
            int b = d >> 7;
            bb[u] = b;
            rk[u] = atomicAdd(&lh[b], 1);
            word[u] = (unsigned int)s | ((unsigned int)(d & 127) << 17);
        }
    }
    __syncthreads();
    for (int b = t; b < NBK; b += 256) {
        int c = lh[b];
        lbase[b] = c ? atomicAdd(&gcur[b], c) : 0;
    }
    __syncthreads();
    #pragma unroll
    for (int u = 0; u < 16; ++u)
        if (bb[u] >= 0) binned[lbase[bb[u]] + rk[u]] = word[u];
}

__global__ __launch_bounds__(256) void k_nodecnt(const unsigned int* __restrict__ binned,
                                                 const int* __restrict__ bko,
                                                 int* __restrict__ cnt, int N) {
    __shared__ int wv[128];
    int b = blockIdx.x, t = threadIdx.x;
    if (t < 128) wv[t] = 0;
    __syncthreads();
    int beg = bko[b], end = bko[b + 1];
    for (int i = beg + t; i < end; i += 256)
        atomicAdd(&wv[binned[i] >> 17], 1);
    __syncthreads();
    int node = (b << 7) + t;
    if (t < 128 && node < N) cnt[node] = wv[t];
}

__global__ __launch_bounds__(1024) void k_scan1(const int* __restrict__ cnt,
                                                int* __restrict__ off,
                                                int* __restrict__ bsum, int N) {
    int i = blockIdx.x * 1024 + threadIdx.x;
    int v = (i < N) ? cnt[i] : 0;
    int lane = threadIdx.x & 63, wid = threadIdx.x >> 6;
    int x = v;
    #pragma unroll
    for (int o = 1; o < 64; o <<= 1) {
        int y = __shfl_up(x, o);
        if (lane >= o) x += y;
    }
    __shared__ int wsum[16];
    if (lane == 63) wsum[wid] = x;
    __syncthreads();
    if (wid == 0) {
        int s = (lane < 16) ? wsum[lane] : 0;
        #pragma unroll
        for (int o = 1; o < 16; o <<= 1) {
            int y = __shfl_up(s, o);
            if (lane >= o) s += y;
        }
        if (lane < 16) wsum[lane] = s;
    }
    __syncthreads();
    int waveoff = (wid > 0) ? wsum[wid - 1] : 0;
    int incl = x + waveoff;
    if (i < N) off[i] = incl - v;
    if (threadIdx.x == 1023) bsum[blockIdx.x] = incl;
}

__global__ void k_scan2(const int* __restrict__ bsum, int* __restrict__ boff,
                        int* __restrict__ off, int N, int nb) {
    int lane = threadIdx.x;
    int v = (lane < nb) ? bsum[lane] : 0;
    int x = v;
    #pragma unroll
    for (int o = 1; o < 64; o <<= 1) {
        int y = __shfl_up(x, o);
        if (lane >= o) x += y;
    }
    if (lane < nb) boff[lane] = x - v;
    if (lane == 63) off[N] = x;
}

__global__ __launch_bounds__(1024) void k_scan3(int* __restrict__ off,
                                                const int* __restrict__ boff, int N) {
    int i = blockIdx.x * 1024 + threadIdx.x;
    if (i >= N) return;
    off[i] += boff[blockIdx.x];
}

__global__ __launch_bounds__(256) void k_scatter2(const unsigned int* __restrict__ binned,
                                                  const int* __restrict__ bko,
                                                  const int* __restrict__ off,
                                                  int* __restrict__ csr, int N) {
    __shared__ int lcur[128];
    int b = blockIdx.x, t = threadIdx.x;
    int n0 = b << 7;
    if (t < 128) lcur[t] = (n0 + t < N) ? off[n0 + t] : 0;
    __syncthreads();
    int beg = bko[b], end = bko[b + 1];
    for (int i = beg + t; i < end; i += 256) {
        unsigned int v = binned[i];
        int pos = atomicAdd(&lcur[v >> 17], 1);
        csr[pos] = (int)(v & 0x1FFFF);
    }
}

// ================= W -> fp16 =================

__global__ __launch_bounds__(256) void k_wconv(const float* __restrict__ W0,
                                               const float* __restrict__ W1,
                                               const float* __restrict__ W2,
                                               _Float16* __restrict__ w16) {
    int i = blockIdx.x * 256 + threadIdx.x;
    if (i >= 3 * 16384) return;
    const float* src = (i < 16384) ? W0 : (i < 32768 ? W1 : W2);
    w16[i] = (_Float16)src[i & 16383];
}

// ================= MFMA fp16 GEMM + fused attention logits =================
// 16x16x32_f16 lane maps (m89-verified):
//   A[m][k]: m=lane&15, k=(lane>>4)*8+j ; B[k][n]: n=lane&15, k=(lane>>4)*8+j
//   C/D[r][c]: c=lane&15, r=(lane>>4)*4+reg

__global__ __launch_bounds__(256) void k_gemm_mfma(const float* __restrict__ X,
                                                   const _Float16* __restrict__ Wh,
                                                   const float* __restrict__ a_src,
                                                   const float* __restrict__ a_dst,
                                                   __half* __restrict__ Hout,
                                                   float* __restrict__ alsrc,
                                                   float* __restrict__ aldst, int N) {
    __shared__ _Float16 As[64][136];   // +8 pad -> 2-way bank aliasing only (free)
    __shared__ float sS[64][2];
    __shared__ float sD[64][2];
    const int t = threadIdx.x;
    const int lane = t & 63, w = t >> 6;
    const int block_row = blockIdx.x * 64;

    if (t < 128) { sS[t >> 1][t & 1] = 0.f; sD[t >> 1][t & 1] = 0.f; }

    // stage X (fp32) -> As (fp16)
    #pragma unroll
    for (int it = 0; it < 8; ++it) {
        int i = t + 256 * it;
        int row = i >> 5, c4 = i & 31;
        int gr = block_row + row;
        float4 xv = make_float4(0.f, 0.f, 0.f, 0.f);
        if (gr < N) xv = *(const float4*)(X + (size_t)gr * 128 + c4 * 4);
        half4v hv;
        hv[0] = (_Float16)xv.x; hv[1] = (_Float16)xv.y;
        hv[2] = (_Float16)xv.z; hv[3] = (_Float16)xv.w;
        *(half4v*)(&As[row][c4 * 4]) = hv;
    }

    // preload B fragments (W16 32 KB, L1/L2-resident)
    const int l15 = lane & 15, kq = (lane >> 4) * 8;
    half8 bf[2][4];
    #pragma unroll
    for (int ntl = 0; ntl < 2; ++ntl) {
        int n0 = (w * 2 + ntl) * 16 + l15;
        #pragma unroll
        for (int kt = 0; kt < 4; ++kt)
            #pragma unroll
            for (int j = 0; j < 8; ++j)
                bf[ntl][kt][j] = Wh[(kt * 32 + kq + j) * 128 + n0];
    }
    __syncthreads();

    float4v acc[4][2];
    #pragma unroll
    for (int mt = 0; mt < 4; ++mt)
        #pragma unroll
        for (int ntl = 0; ntl < 2; ++ntl)
            acc[mt][ntl] = (float4v){0.f, 0.f, 0.f, 0.f};

    #pragma unroll
    for (int kt = 0; kt < 4; ++kt) {
        half8 a[4];
        #pragma unroll
        for (int mt = 0; mt < 4; ++mt)
            a[mt] = *(const half8*)(&As[mt * 16 + l15][kt * 32 + kq]);
        #pragma unroll
        for (int mt = 0; mt < 4; ++mt)
            #pragma unroll
            for (int ntl = 0; ntl < 2; ++ntl)
                acc[mt][ntl] = __builtin_amdgcn_mfma_f32_16x16x32_f16(
                    a[mt], bf[ntl][kt], acc[mt][ntl], 0, 0, 0);
    }

    // write h16
    #pragma unroll
    for (int mt = 0; mt < 4; ++mt) {
        int r0 = block_row + mt * 16 + (lane >> 4) * 4;
        #pragma unroll
        for (int ntl = 0; ntl < 2; ++ntl) {
            int col = (w * 2 + ntl) * 16 + l15;
            #pragma unroll
            for (int reg = 0; reg < 4; ++reg) {
                int r = r0 + reg;
                if (r < N) Hout[(size_t)r * 128 + col] = __float2half((float)acc[mt][ntl][reg]);
            }
        }
    }

    // fused attention logits: this wave covers cols [w*32, w*32+32) -> head = w>>1
    {
        int c0 = w * 32 + l15, c1 = c0 + 16;
        float as0 = a_src[c0], as1 = a_src[c1];
        float ad0 = a_dst[c0], ad1 = a_dst[c1];
        int head = w >> 1;
        #pragma unroll
        for (int mt = 0; mt < 4; ++mt) {
            #pragma unroll
            for (int reg = 0; reg < 4; ++reg) {
                float ps = (float)acc[mt][0][reg] * as0 + (float)acc[mt][1][reg] * as1;
                float pd = (float)acc[mt][0][reg] * ad0 + (float)acc[mt][1][reg] * ad1;
                #pragma unroll
                for (int o = 1; o < 16; o <<= 1) {
                    ps += __shfl_xor(ps, o);
                    pd += __shfl_xor(pd, o);
                }
                if (l15 == 0) {
                    int row = mt * 16 + (lane >> 4) * 4 + reg;
                    atomicAdd(&sS[row][head], ps);
                    atomicAdd(&sD[row][head], pd);
                }
            }
        }
    }
    __syncthreads();
    if (t < 128) {
        int row = t >> 1, head = t & 1;
        int gr = block_row + row;
        if (gr < N) {
            alsrc[gr * 2 + head] = sS[row][head];
            aldst[gr * 2 + head] = sD[row][head];
        }
    }
}

// ================= softmax-aggregate (one wave64 per dst node) =================

__global__ __launch_bounds__(256) void k_aggregate(
        const __half* __restrict__ H16,
        const float* __restrict__ alsrc,
        const float* __restrict__ aldst,
        const int* __restrict__ off, const int* __restrict__ csr,
        const float* __restrict__ bias,
        const float* __restrict__ prev,
        float* __restrict__ Out, int N, int mode) {
    int node = (int)((blockIdx.x * 256 + threadIdx.x) >> 6);
    int lane = threadIdx.x & 63;
    if (node >= N) return;
    int beg = off[node], end = off[node + 1];
    float ad0 = aldst[node * 2], ad1 = aldst[node * 2 + 1];

    int p = lane & 15;
    int q = lane >> 4;
    bool head0 = p < 8;

    float acc[8];
    #pragma unroll
    for (int i = 0; i < 8; ++i) acc[i] = 0.f;
    float dsum = 0.f;

    for (int base = beg; base < end; base += 64) {
        int i = base + lane;
        float w0 = 0.f, w1 = 0.f; int s = 0;
        if (i < end) {
            s = csr[i];
            float2 al = *(const float2*)(&alsrc[s * 2]);
            float e0 = al.x + ad0; e0 = e0 > 0.f ? e0 : LEAK * e0;
            float e1 = al.y + ad1; e1 = e1 > 0.f ? e1 : LEAK * e1;
            w0 = __expf(e0); w1 = __expf(e1);
        }
        int cnt = min(64, end - base);
        int iters = (cnt + 3) >> 2;
        for (int jj = 0; jj < iters; ++jj) {
            int sl = (jj << 2) + q;
            int   sj  = __shfl(s,  sl);
            float w0j = __shfl(w0, sl);
            float w1j = __shfl(w1, sl);
            float wsel = head0 ? w0j : w1j;
            const __half2* hp = (const __half2*)(H16 + (size_t)sj * 128 + p * 8);
            uint4 raw = *(const uint4*)hp;
            const __half2* hh = (const __half2*)&raw;
            #pragma unroll
            for (int tt = 0; tt < 4; ++tt) {
                float2 f = __half22float2(hh[tt]);
                acc[2 * tt]     += wsel * f.x;
                acc[2 * tt + 1] += wsel * f.y;
            }
            dsum += wsel;
        }
    }

    #pragma unroll
    for (int i = 0; i < 8; ++i) {
        acc[i] += __shfl_xor(acc[i], 16);
        acc[i] += __shfl_xor(acc[i], 32);
    }
    dsum += __shfl_xor(dsum, 16);
    dsum += __shfl_xor(dsum, 32);

    if (q == 0) {
        float inv = 1.f / dsum;
        int c0 = p * 8;
        float v[8];
        #pragma unroll
        for (int i = 0; i < 8; ++i) v[i] = acc[i] * inv + bias[c0 + i];
        if (mode) {
            float4 p0 = *(const float4*)(&prev[(size_t)node * 128 + c0]);
            float4 p1 = *(const float4*)(&prev[(size_t)node * 128 + c0 + 4]);
            v[0] += p0.x; v[1] += p0.y; v[2] += p0.z; v[3] += p0.w;
            v[4] += p1.x; v[5] += p1.y; v[6] += p1.z; v[7] += p1.w;
        }
        #pragma unroll
        for (int i = 0; i < 8; ++i) v[i] = v[i] > 0.f ? v[i] : LEAK * v[i];
        *(float4*)(&Out[(size_t)node * 128 + c0])     = make_float4(v[0], v[1], v[2], v[3]);
        *(float4*)(&Out[(size_t)node * 128 + c0 + 4]) = make_float4(v[4], v[5], v[6], v[7]);
    }
}

// ================= final linear =================

__global__ __launch_bounds__(256) void k_final(const float* __restrict__ Hm,
                                               const float* __restrict__ lw,
                                               const float* __restrict__ lb,
                                               float* __restrict__ outp, int N) {
    int node = (int)((blockIdx.x * 256 + threadIdx.x) >> 6);
    int lane = threadIdx.x & 63;
    if (node >= N) return;
    float2 h = *(const float2*)(&Hm[(size_t)node * 128 + lane * 2]);
    float2 w = *(const float2*)(&lw[lane * 2]);
    float v = h.x * w.x + h.y * w.y;
    #pragma unroll
    for (int o = 32; o > 0; o >>= 1) v += __shfl_xor(v, o);
    if (lane == 0) outp[node] = v + lb[0];
}

// ================= launch =================

extern "C" void kernel_launch(void* const* d_in, const int* in_sizes, int n_in,
                              void* d_out, int out_size, void* d_ws, size_t ws_size,
                              hipStream_t stream) {
    const float* x    = (const float*)d_in[0];
    const int*   edge = (const int*)d_in[1];
    const float* W[3]  = {(const float*)d_in[2], (const float*)d_in[6], (const float*)d_in[10]};
    const float* as[3] = {(const float*)d_in[3], (const float*)d_in[7], (const float*)d_in[11]};
    const float* ad[3] = {(const float*)d_in[4], (const float*)d_in[8], (const float*)d_in[12]};
    const float* bs[3] = {(const float*)d_in[5], (const float*)d_in[9], (const float*)d_in[13]};
    const float* lw = (const float*)d_in[14];
    const float* lb = (const float*)d_in[15];

    const int N    = in_sizes[0] / 128;
    const int E    = in_sizes[1] / 2;
    const int ETOT = E + N;
    const int NBK  = (N + 127) >> 7;   // requires N <= 65536 (here N = 50000)

    char* base = (char*)d_ws;
    size_t o = 0;
    auto carve = [&](size_t bytes) {
        char* p = base + o;
        o = (o + bytes + 255) & ~(size_t)255;
        return p;
    };
    int*      cnt    = (int*)     carve((size_t)N * 4);
    int*      off    = (int*)     carve((size_t)(N + 1) * 4);
    int*      boff   = (int*)     carve(64 * 4);
    int*      bsum   = (int*)     carve(64 * 4);
    int*      gbkt   = (int*)     carve((size_t)(NBK + 1) * 4);
    int*      bko    = (int*)     carve((size_t)(NBK + 1) * 4);
    int*      gcur   = (int*)     carve((size_t)(NBK + 1) * 4);
    unsigned* binned = (unsigned*)carve((size_t)ETOT * 4);
    int*      csr    = (int*)     carve((size_t)ETOT * 4);
    float*    alsrc  = (float*)   carve((size_t)N * 2 * 4);
    float*    aldst  = (float*)   carve((size_t)N * 2 * 4);
    __half*   h16    = (__half*)  carve((size_t)N * 128 * 2);
    float*    bufA   = (float*)   carve((size_t)N * 128 * 4);
    float*    bufB   = (float*)   carve((size_t)N * 128 * 4);
    _Float16* w16    = (_Float16*)carve((size_t)3 * 16384 * 2);
    (void)ws_size; (void)n_in; (void)out_size;

    const int* esrc = edge;
    const int* edst = edge + E;

    int nb = (N + 1023) / 1024;
    int eb = (ETOT + 4095) / 4096;

    hipMemsetAsync(gbkt, 0, (size_t)(NBK + 1) * 4, stream);
    k_wconv<<<192, 256, 0, stream>>>(W[0], W[1], W[2], w16);

    // bucketed CSR build
    k_bincount<<<eb, 256, 0, stream>>>(edst, gbkt, E, ETOT, NBK);
    k_bktscan<<<1, 512, 0, stream>>>(gbkt, bko, gcur, NBK);
    k_binscatter<<<eb, 256, 0, stream>>>(esrc, edst, gcur, binned, E, ETOT, NBK);
    k_nodecnt<<<NBK, 256, 0, stream>>>(binned, bko, cnt, N);
    k_scan1<<<nb, 1024, 0, stream>>>(cnt, off, bsum, N);
    k_scan2<<<1, 64, 0, stream>>>(bsum, boff, off, N, nb);
    k_scan3<<<nb, 1024, 0, stream>>>(off, boff, N);
    k_scatter2<<<NBK, 256, 0, stream>>>(binned, bko, off, csr, N);

    int gemm_blocks = (N + 63) / 64;
    int node_blocks = (N * 64 + 255) / 256;

    // layer 1
    k_gemm_mfma<<<gemm_blocks, 256, 0, stream>>>(x, w16, as[0], ad[0], h16, alsrc, aldst, N);
    k_aggregate<<<node_blocks, 256, 0, stream>>>(h16, alsrc, aldst, off, csr,
                                                 bs[0], nullptr, bufA, N, 0);
    // layer 2
    k_gemm_mfma<<<gemm_blocks, 256, 0, stream>>>(bufA, w16 + 16384, as[1], ad[1], h16, alsrc, aldst, N);
    k_aggregate<<<node_blocks, 256, 0, stream>>>(h16, alsrc, aldst, off, csr,
                                                 bs[1], bufA, bufB, N, 1);
    // layer 3
    k_gemm_mfma<<<gemm_blocks, 256, 0, stream>>>(bufB, w16 + 32768, as[2], ad[2], h16, alsrc, aldst, N);
    k_aggregate<<<node_blocks, 256, 0, stream>>>(h16, alsrc, aldst, off, csr,
                                                 bs[2], bufB, bufA, N, 1);

    k_final<<<node_blocks, 256, 0, stream>>>(bufA, lw, lb, (float*)d_out, N);
}

// Round 5
// 315.019 us; speedup vs baseline: 1.9480x; 1.0405x over previous
//
#include <hip/hip_runtime.h>
#include <hip/hip_bf16.h>
#include <hip/hip_fp16.h>

#define LEAK 0.2f

typedef _Float16 half8  __attribute__((ext_vector_type(8)));
typedef _Float16 half4v __attribute__((ext_vector_type(4)));
typedef float    float4v __attribute__((ext_vector_type(4)));

// ================= bucketed CSR build =================
// bucket b = dst >> 7 (128 nodes/bucket). NBK <= 512. packed: src | (dloc<<17)

__global__ __launch_bounds__(256) void k_bincount(const int* __restrict__ edst,
                                                  int* __restrict__ gbkt,
                                                  int E, int ETOT, int NBK) {
    __shared__ int lh[512];
    int t = threadIdx.x;
    for (int b = t; b < NBK; b += 256) lh[b] = 0;
    __syncthreads();
    int base = blockIdx.x * 4096;
    #pragma unroll
    for (int u = 0; u < 16; ++u) {
        int e = base + u * 256 + t;
        if (e < ETOT) {
            int d = (e < E) ? edst[e] : (e - E);
            atomicAdd(&lh[d >> 7], 1);
        }
    }
    __syncthreads();
    for (int b = t; b < NBK; b += 256)
        if (lh[b]) atomicAdd(&gbkt[b], lh[b]);
}

__global__ __launch_bounds__(512) void k_bktscan(const int* __restrict__ gbkt,
                                                 int* __restrict__ bko,
                                                 int* __restrict__ gcur, int NBK) {
    int t = threadIdx.x;
    int v = (t < NBK) ? gbkt[t] : 0;
    int lane = t & 63, wid = t >> 6;
    int x = v;
    #pragma unroll
    for (int o = 1; o < 64; o <<= 1) {
        int y = __shfl_up(x, o);
        if (lane >= o) x += y;
    }
    __shared__ int ws[8];
    if (lane == 63) ws[wid] = x;
    __syncthreads();
    if (wid == 0) {
        int s = (lane < 8) ? ws[lane] : 0;
        #pragma unroll
        for (int o = 1; o < 8; o <<= 1) {
            int y = __shfl_up(s, o);
            if (lane >= o) s += y;
        }
        if (lane < 8) ws[lane] = s;
    }
    __syncthreads();
    int excl = x - v + (wid > 0 ? ws[wid - 1] : 0);
    if (t < NBK) { bko[t] = excl; gcur[t] = excl; }
    if (t == 511) bko[NBK] = excl;   // v==0 here -> grand total
}

__global__ __launch_bounds__(256) void k_binscatter(const int* __restrict__ esrc,
                                                    const int* __restrict__ edst,
                                                    int* __restrict__ gcur,
                                                    unsigned int* __restrict__ binned,
                                                    int E, int ETOT, int NBK) {
    __shared__ int lh[512];
    __shared__ int lbase[512];
    int t = threadIdx.x;
    for (int b = t; b < NBK; b += 256) lh[b] = 0;
    __syncthreads();
    int base = blockIdx.x * 4096;
    unsigned int word[16]; int bb[16], rk[16];
    #pragma unroll
    for (int u = 0; u < 16; ++u) {
        int e = base + u * 256 + t;
        bb[u] = -1;
        if (e < ETOT) {
            int s, d;
            if (e < E) { s = esrc[e]; d = edst[e]; } else { s = d = e - E; }
            int b = d >> 7;
            bb[u] = b;
            rk[u] = atomicAdd(&lh[b], 1);
            word[u] = (unsigned int)s | ((unsigned int)(d & 127) << 17);
        }
    }
    __syncthreads();
    for (int b = t; b < NBK; b += 256) {
        int c = lh[b];
        lbase[b] = c ? atomicAdd(&gcur[b], c) : 0;
    }
    __syncthreads();
    #pragma unroll
    for (int u = 0; u < 16; ++u)
        if (bb[u] >= 0) binned[lbase[bb[u]] + rk[u]] = word[u];
}

// fused: per-bucket degree count + LDS scan -> off[] + scatter into csr
__global__ __launch_bounds__(256) void k_scatter2(const unsigned int* __restrict__ binned,
                                                  const int* __restrict__ bko,
                                                  int* __restrict__ off,
                                                  int* __restrict__ csr, int N, int NBK) {
    __shared__ int deg[128];
    __shared__ int lcur[128];
    __shared__ int wt[2];
    int b = blockIdx.x, t = threadIdx.x;
    int n0 = b << 7;
    if (t < 128) deg[t] = 0;
    __syncthreads();
    int beg = bko[b], end = bko[b + 1];
    for (int i = beg + t; i < end; i += 256)
        atomicAdd(&deg[binned[i] >> 17], 1);
    __syncthreads();
    int v = 0, x = 0;
    if (t < 128) {
        v = deg[t];
        x = v;
        int lane = t & 63;
        #pragma unroll
        for (int o = 1; o < 64; o <<= 1) {
            int y = __shfl_up(x, o);
            if (lane >= o) x += y;
        }
        if (lane == 63) wt[t >> 6] = x;
    }
    __syncthreads();
    if (t < 128) {
        int excl = x - v + ((t >= 64) ? wt[0] : 0) + beg;
        lcur[t] = excl;
        int node = n0 + t;
        if (node < N) off[node] = excl;
    }
    if (b == NBK - 1 && t == 0) off[N] = end;
    __syncthreads();
    for (int i = beg + t; i < end; i += 256) {
        unsigned int u = binned[i];
        int pos = atomicAdd(&lcur[u >> 17], 1);
        csr[pos] = (int)(u & 0x1FFFF);
    }
}

// ================= W -> fp16 =================

__global__ __launch_bounds__(256) void k_wconv(const float* __restrict__ W0,
                                               const float* __restrict__ W1,
                                               const float* __restrict__ W2,
                                               _Float16* __restrict__ w16) {
    int i = blockIdx.x * 256 + threadIdx.x;
    if (i >= 3 * 16384) return;
    const float* src = (i < 16384) ? W0 : (i < 32768 ? W1 : W2);
    w16[i] = (_Float16)src[i & 16383];
}

// ================= MFMA fp16 GEMM + fused attention logits =================
// 16x16x32_f16 lane maps (m89-verified):
//   A[m][k]: m=lane&15, k=(lane>>4)*8+j ; B[k][n]: n=lane&15, k=(lane>>4)*8+j
//   C/D[r][c]: c=lane&15, r=(lane>>4)*4+reg

__global__ __launch_bounds__(256) void k_gemm_mfma(const float* __restrict__ X,
                                                   const _Float16* __restrict__ Wh,
                                                   const float* __restrict__ a_src,
                                                   const float* __restrict__ a_dst,
                                                   __half* __restrict__ Hout,
                                                   float* __restrict__ alsrc,
                                                   float* __restrict__ aldst, int N) {
    __shared__ _Float16 As[64][136];   // +8 pad -> 2-way bank aliasing only (free)
    __shared__ float sS[64][2];
    __shared__ float sD[64][2];
    const int t = threadIdx.x;
    const int lane = t & 63, w = t >> 6;
    const int block_row = blockIdx.x * 64;

    if (t < 128) { sS[t >> 1][t & 1] = 0.f; sD[t >> 1][t & 1] = 0.f; }

    #pragma unroll
    for (int it = 0; it < 8; ++it) {
        int i = t + 256 * it;
        int row = i >> 5, c4 = i & 31;
        int gr = block_row + row;
        float4 xv = make_float4(0.f, 0.f, 0.f, 0.f);
        if (gr < N) xv = *(const float4*)(X + (size_t)gr * 128 + c4 * 4);
        half4v hv;
        hv[0] = (_Float16)xv.x; hv[1] = (_Float16)xv.y;
        hv[2] = (_Float16)xv.z; hv[3] = (_Float16)xv.w;
        *(half4v*)(&As[row][c4 * 4]) = hv;
    }

    const int l15 = lane & 15, kq = (lane >> 4) * 8;
    half8 bf[2][4];
    #pragma unroll
    for (int ntl = 0; ntl < 2; ++ntl) {
        int n0 = (w * 2 + ntl) * 16 + l15;
        #pragma unroll
        for (int kt = 0; kt < 4; ++kt)
            #pragma unroll
            for (int j = 0; j < 8; ++j)
                bf[ntl][kt][j] = Wh[(kt * 32 + kq + j) * 128 + n0];
    }
    __syncthreads();

    float4v acc[4][2];
    #pragma unroll
    for (int mt = 0; mt < 4; ++mt)
        #pragma unroll
        for (int ntl = 0; ntl < 2; ++ntl)
            acc[mt][ntl] = (float4v){0.f, 0.f, 0.f, 0.f};

    #pragma unroll
    for (int kt = 0; kt < 4; ++kt) {
        half8 a[4];
        #pragma unroll
        for (int mt = 0; mt < 4; ++mt)
            a[mt] = *(const half8*)(&As[mt * 16 + l15][kt * 32 + kq]);
        #pragma unroll
        for (int mt = 0; mt < 4; ++mt)
            #pragma unroll
            for (int ntl = 0; ntl < 2; ++ntl)
                acc[mt][ntl] = __builtin_amdgcn_mfma_f32_16x16x32_f16(
                    a[mt], bf[ntl][kt], acc[mt][ntl], 0, 0, 0);
    }

    #pragma unroll
    for (int mt = 0; mt < 4; ++mt) {
        int r0 = block_row + mt * 16 + (lane >> 4) * 4;
        #pragma unroll
        for (int ntl = 0; ntl < 2; ++ntl) {
            int col = (w * 2 + ntl) * 16 + l15;
            #pragma unroll
            for (int reg = 0; reg < 4; ++reg) {
                int r = r0 + reg;
                if (r < N) Hout[(size_t)r * 128 + col] = __float2half((float)acc[mt][ntl][reg]);
            }
        }
    }

    // fused attention logits
    {
        int c0 = w * 32 + l15, c1 = c0 + 16;
        float as0 = a_src[c0], as1 = a_src[c1];
        float ad0 = a_dst[c0], ad1 = a_dst[c1];
        int head = w >> 1;
        #pragma unroll
        for (int mt = 0; mt < 4; ++mt) {
            #pragma unroll
            for (int reg = 0; reg < 4; ++reg) {
                float ps = (float)acc[mt][0][reg] * as0 + (float)acc[mt][1][reg] * as1;
                float pd = (float)acc[mt][0][reg] * ad0 + (float)acc[mt][1][reg] * ad1;
                #pragma unroll
                for (int o = 1; o < 16; o <<= 1) {
                    ps += __shfl_xor(ps, o);
                    pd += __shfl_xor(pd, o);
                }
                if (l15 == 0) {
                    int row = mt * 16 + (lane >> 4) * 4 + reg;
                    atomicAdd(&sS[row][head], ps);
                    atomicAdd(&sD[row][head], pd);
                }
            }
        }
    }
    __syncthreads();
    if (t < 128) {
        int row = t >> 1, head = t & 1;
        int gr = block_row + row;
        if (gr < N) {
            alsrc[gr * 2 + head] = sS[row][head];
            aldst[gr * 2 + head] = sD[row][head];
        }
    }
}

// ================= softmax-aggregate: one wave64 per dst node, 8 edges/iter ===========
// lane: p=lane&7 owns channels [16p,16p+16); q=lane>>3 processes edges == q (mod 8).
// mode: 0 = write Out ; 1 = +residual, write Out ; 2 = +residual, fused final dot -> logits

__global__ __launch_bounds__(256) void k_aggregate(
        const __half* __restrict__ H16,
        const float* __restrict__ alsrc,
        const float* __restrict__ aldst,
        const int* __restrict__ off, const int* __restrict__ csr,
        const float* __restrict__ bias,
        const float* __restrict__ prev,
        float* __restrict__ Out,
        const float* __restrict__ lw, const float* __restrict__ lb,
        float* __restrict__ logits, int N, int mode) {
    int node = (int)((blockIdx.x * 256 + threadIdx.x) >> 6);
    int lane = threadIdx.x & 63;
    if (node >= N) return;
    int beg = off[node], end = off[node + 1];
    float ad0 = aldst[node * 2], ad1 = aldst[node * 2 + 1];

    int p = lane & 7;
    int q = lane >> 3;
    bool head0 = p < 4;
    const _Float16* hbase = (const _Float16*)H16 + p * 16;

    float acc[16];
    #pragma unroll
    for (int i = 0; i < 16; ++i) acc[i] = 0.f;
    float dsum = 0.f;

    for (int base = beg; base < end; base += 64) {
        int i = base + lane;
        float w0 = 0.f, w1 = 0.f; int s = 0;
        if (i < end) {
            s = csr[i];
            float2 al = *(const float2*)(&alsrc[s * 2]);
            float e0 = al.x + ad0; e0 = e0 > 0.f ? e0 : LEAK * e0;
            float e1 = al.y + ad1; e1 = e1 > 0.f ? e1 : LEAK * e1;
            w0 = __expf(e0); w1 = __expf(e1);
        }
        int cnt = min(64, end - base);
        int iters = (cnt + 7) >> 3;
        for (int jj = 0; jj < iters; ++jj) {
            int sl = (jj << 3) + q;
            int   sj  = __shfl(s,  sl);
            float w0j = __shfl(w0, sl);
            float w1j = __shfl(w1, sl);
            float wsel = head0 ? w0j : w1j;   // 0 for tail slots
            const _Float16* hp = hbase + (size_t)sj * 128;
            uint4 r0 = *(const uint4*)hp;        // 8 fp16
            uint4 r1 = *(const uint4*)(hp + 8);  // 8 fp16
            const _Float16* ha = (const _Float16*)&r0;
            const _Float16* hb = (const _Float16*)&r1;
            #pragma unroll
            for (int k = 0; k < 8; ++k) acc[k]     += wsel * (float)ha[k];
            #pragma unroll
            for (int k = 0; k < 8; ++k) acc[8 + k] += wsel * (float)hb[k];
            dsum += wsel;
        }
    }

    #pragma unroll
    for (int i = 0; i < 16; ++i) {
        acc[i] += __shfl_xor(acc[i], 8);
        acc[i] += __shfl_xor(acc[i], 16);
        acc[i] += __shfl_xor(acc[i], 32);
    }
    dsum += __shfl_xor(dsum, 8);
    dsum += __shfl_xor(dsum, 16);
    dsum += __shfl_xor(dsum, 32);

    if (q == 0) {
        float inv = 1.f / dsum;
        int c0 = p * 16;
        float v[16];
        #pragma unroll
        for (int i = 0; i < 16; ++i) v[i] = acc[i] * inv + bias[c0 + i];
        if (mode >= 1) {
            #pragma unroll
            for (int g = 0; g < 4; ++g) {
                float4 pv = *(const float4*)(&prev[(size_t)node * 128 + c0 + 4 * g]);
                v[4 * g]     += pv.x; v[4 * g + 1] += pv.y;
                v[4 * g + 2] += pv.z; v[4 * g + 3] += pv.w;
            }
        }
        #pragma unroll
        for (int i = 0; i < 16; ++i) v[i] = v[i] > 0.f ? v[i] : LEAK * v[i];
        if (mode == 2) {
            float partial = 0.f;
            #pragma unroll
            for (int i = 0; i < 16; ++i) partial += v[i] * lw[c0 + i];
            partial += __shfl_xor(partial, 1);
            partial += __shfl_xor(partial, 2);
            partial += __shfl_xor(partial, 4);
            if (p == 0) logits[node] = partial + lb[0];
        } else {
            #pragma unroll
            for (int g = 0; g < 4; ++g)
                *(float4*)(&Out[(size_t)node * 128 + c0 + 4 * g]) =
                    make_float4(v[4 * g], v[4 * g + 1], v[4 * g + 2], v[4 * g + 3]);
        }
    }
}

// ================= launch =================

extern "C" void kernel_launch(void* const* d_in, const int* in_sizes, int n_in,
                              void* d_out, int out_size, void* d_ws, size_t ws_size,
                              hipStream_t stream) {
    const float* x    = (const float*)d_in[0];
    const int*   edge = (const int*)d_in[1];
    const float* W[3]  = {(const float*)d_in[2], (const float*)d_in[6], (const float*)d_in[10]};
    const float* as[3] = {(const float*)d_in[3], (const float*)d_in[7], (const float*)d_in[11]};
    const float* ad[3] = {(const float*)d_in[4], (const float*)d_in[8], (const float*)d_in[12]};
    const float* bs[3] = {(const float*)d_in[5], (const float*)d_in[9], (const float*)d_in[13]};
    const float* lw = (const float*)d_in[14];
    const float* lb = (const float*)d_in[15];

    const int N    = in_sizes[0] / 128;
    const int E    = in_sizes[1] / 2;
    const int ETOT = E + N;
    const int NBK  = (N + 127) >> 7;   // requires N <= 65536 (here N = 50000)

    char* base = (char*)d_ws;
    size_t o = 0;
    auto carve = [&](size_t bytes) {
        char* p = base + o;
        o = (o + bytes + 255) & ~(size_t)255;
        return p;
    };
    int*      off    = (int*)     carve((size_t)(N + 1) * 4);
    int*      gbkt   = (int*)     carve((size_t)(NBK + 1) * 4);
    int*      bko    = (int*)     carve((size_t)(NBK + 1) * 4);
    int*      gcur   = (int*)     carve((size_t)(NBK + 1) * 4);
    unsigned* binned = (unsigned*)carve((size_t)ETOT * 4);
    int*      csr    = (int*)     carve((size_t)ETOT * 4);
    float*    alsrc  = (float*)   carve((size_t)N * 2 * 4);
    float*    aldst  = (float*)   carve((size_t)N * 2 * 4);
    __half*   h16    = (__half*)  carve((size_t)N * 128 * 2);
    float*    bufA   = (float*)   carve((size_t)N * 128 * 4);
    float*    bufB   = (float*)   carve((size_t)N * 128 * 4);
    _Float16* w16    = (_Float16*)carve((size_t)3 * 16384 * 2);
    (void)ws_size; (void)n_in; (void)out_size;

    const int* esrc = edge;
    const int* edst = edge + E;

    int eb = (ETOT + 4095) / 4096;

    hipMemsetAsync(gbkt, 0, (size_t)(NBK + 1) * 4, stream);
    k_wconv<<<192, 256, 0, stream>>>(W[0], W[1], W[2], w16);

    // bucketed CSR build (5 dispatches total)
    k_bincount<<<eb, 256, 0, stream>>>(edst, gbkt, E, ETOT, NBK);
    k_bktscan<<<1, 512, 0, stream>>>(gbkt, bko, gcur, NBK);
    k_binscatter<<<eb, 256, 0, stream>>>(esrc, edst, gcur, binned, E, ETOT, NBK);
    k_scatter2<<<NBK, 256, 0, stream>>>(binned, bko, off, csr, N, NBK);

    int gemm_blocks = (N + 63) / 64;
    int node_blocks = (N * 64 + 255) / 256;

    // layer 1
    k_gemm_mfma<<<gemm_blocks, 256, 0, stream>>>(x, w16, as[0], ad[0], h16, alsrc, aldst, N);
    k_aggregate<<<node_blocks, 256, 0, stream>>>(h16, alsrc, aldst, off, csr,
                                                 bs[0], nullptr, bufA, lw, lb, nullptr, N, 0);
    // layer 2
    k_gemm_mfma<<<gemm_blocks, 256, 0, stream>>>(bufA, w16 + 16384, as[1], ad[1], h16, alsrc, aldst, N);
    k_aggregate<<<node_blocks, 256, 0, stream>>>(h16, alsrc, aldst, off, csr,
                                                 bs[1], bufA, bufB, lw, lb, nullptr, N, 1);
    // layer 3 (+ fused final linear)
    k_gemm_mfma<<<gemm_blocks, 256, 0, stream>>>(bufB, w16 + 32768, as[2], ad[2], h16, alsrc, aldst, N);
    k_aggregate<<<node_blocks, 256, 0, stream>>>(h16, alsrc, aldst, off, csr,
                                                 bs[2], bufB, nullptr, lw, lb, (float*)d_out, N, 2);
}